// Round 1
// baseline (1148.789 us; speedup 1.0000x reference)
//
#include <hip/hip_runtime.h>

// CNF forward: 8 fixed dopri5 steps x 6 stages, rows independent.
// R6 (occupancy round): R5 ran at 2 waves/EU (pinned + 108 KB LDS -> 1 WG/CU)
// with VALUBusy 52% / MfmaUtil 15% -- latency-bound, both pipes half idle.
// Changes:
//  * 256-thread blocks (one 4-wave group, 16 rows), 2048 blocks. Barriers span
//    4 waves, independent blocks slide past each other's sync points.
//  * All weight fragments (w1f/w2f/aw) loaded DIRECTLY from global (L2-resident,
//    init-only) -- the 75 KB of init-only weight-staging LDS is gone.
//  * sScr transpose eliminated: operand-swapped MFMA16(w1f, ae) yields
//    (e@W1a)^T = C[j=quad*4+rg][b=l16] directly (A/B frags share a register
//    format, so swapping operands transposes the product).
//  * b1/W1_t row: one register per thread; per-stage sBW via single fma+store.
// LDS = 12 KB, __launch_bounds__(256,5) caps VGPR at 102 (was 88) ->
// 5 blocks/CU = 20 waves/CU (was 8). Target: VALUBusy -> ~80%.

typedef __bf16 bf16x8 __attribute__((ext_vector_type(8)));
typedef __bf16 bf16x4 __attribute__((ext_vector_type(4)));
typedef float  f32x4  __attribute__((ext_vector_type(4)));
typedef unsigned int u32;

#define MFMA16(a, b, c) __builtin_amdgcn_mfma_f32_16x16x32_bf16((a), (b), (c), 0, 0, 0)

__device__ __forceinline__ u32 bfbits(float x) {
    __bf16 b = (__bf16)x;                      // RNE fp32->bf16
    return (u32)__builtin_bit_cast(unsigned short, b);
}
__device__ __forceinline__ float frombits(u32 u16) {
    return __builtin_bit_cast(float, u16 << 16);
}
__device__ __forceinline__ u32 pack2(float lo, float hi) {
    return bfbits(lo) | (bfbits(hi) << 16);
}
__device__ __forceinline__ float fast_tanh(float x) {
    float e = __expf(2.0f * x);
    return 1.0f - 2.0f * __builtin_amdgcn_rcpf(e + 1.0f);
}

extern "C" __global__ void __launch_bounds__(256, 5)
cnf_kernel(const float* __restrict__ Yg, const float* __restrict__ Eg,
           const float* __restrict__ W1g, const float* __restrict__ b1g,
           const float* __restrict__ W2g, const float* __restrict__ b2g,
           float* __restrict__ Og)
{
    // ---- LDS (12 KB; 5 WG/CU) ----
    __shared__ __align__(16) __bf16 sY[16 * 72];    // y buf [batch][d]
    __shared__ __align__(16) __bf16 sH[16 * 264];   // h buf [batch][j]
    __shared__ float sBW[256];                      // per-stage b1 + t*W1_t
    __shared__ float sRedSS[64], sRedLP[64];

    const int tid  = threadIdx.x;
    const int wave = tid >> 6;        // 0..3: wave's slot within the group
    const int lane = tid & 63;
    const int quad = lane >> 4;
    const int l16  = lane & 15;
    const int colb = wave * 16;       // own output-col tile base
    const int jb   = wave * 64;       // own hidden-j base (4 tiles of 16)
    const int row  = blockIdx.x * 16 + l16;   // this lane's batch row

    // ---------------- e fragments direct from global ----------------
    // ae: lane (l16=batch, quad) holds e[row][d = quad*8 + i] (+32 for ae1)
    bf16x8 ae0, ae1;
    {
        f32x4 ea = *(const f32x4*)(Eg + row * 64 + quad * 8);
        f32x4 eb = *(const f32x4*)(Eg + row * 64 + quad * 8 + 4);
        f32x4 ec = *(const f32x4*)(Eg + row * 64 + 32 + quad * 8);
        f32x4 ed = *(const f32x4*)(Eg + row * 64 + 32 + quad * 8 + 4);
        ae0[0]=(__bf16)ea[0]; ae0[1]=(__bf16)ea[1]; ae0[2]=(__bf16)ea[2]; ae0[3]=(__bf16)ea[3];
        ae0[4]=(__bf16)eb[0]; ae0[5]=(__bf16)eb[1]; ae0[6]=(__bf16)eb[2]; ae0[7]=(__bf16)eb[3];
        ae1[0]=(__bf16)ec[0]; ae1[1]=(__bf16)ec[1]; ae1[2]=(__bf16)ec[2]; ae1[3]=(__bf16)ec[3];
        ae1[4]=(__bf16)ed[0]; ae1[5]=(__bf16)ed[1]; ae1[6]=(__bf16)ed[2]; ae1[7]=(__bf16)ed[3];
    }

    // ---------------- W1 fragments direct from global (A-op: [m=j][k=d]) ----
    // w1f[t*2+h][i] = W1^T[j = jb+t*16+l16][d = h*32+quad*8+i] = W1g[d*256 + j]
    bf16x8 w1f[8];
#pragma unroll
    for (int t = 0; t < 4; ++t) {
#pragma unroll
        for (int h = 0; h < 2; ++h) {
            const float* src = W1g + (h * 32 + quad * 8) * 256 + jb + t * 16 + l16;
            bf16x8 f;
#pragma unroll
            for (int i = 0; i < 8; ++i) f[i] = (__bf16)src[i * 256];
            w1f[t * 2 + h] = f;
        }
    }

    // ---------------- ghv[j][batch] = gh0 .* v, layout j=quad*4+rg, batch=l16 ----
    // v^T = (e@W1a)^T via operand swap: A=W1a^T[m=j][k=d], B=e^T[k=d][n=b]
    //   -> C[j=quad*4+rg][b=l16]  (no transpose scratch needed)
    // gh0^T = W2@e^T: A=W2[m=j][k=d] (contiguous rows of W2g), B=e^T
    u32 ghvp[8];   // [tile*2 + pair], bf16x2 packed
#pragma unroll
    for (int t = 0; t < 4; ++t) {
        f32x4 vacc = {0.f, 0.f, 0.f, 0.f};
        vacc = MFMA16(w1f[t * 2 + 0], ae0, vacc);
        vacc = MFMA16(w1f[t * 2 + 1], ae1, vacc);
        const float* wr = W2g + (jb + t * 16 + l16) * 64;
        f32x4 p0 = *(const f32x4*)(wr + quad * 8);
        f32x4 p1 = *(const f32x4*)(wr + quad * 8 + 4);
        f32x4 p2 = *(const f32x4*)(wr + 32 + quad * 8);
        f32x4 p3 = *(const f32x4*)(wr + 32 + quad * 8 + 4);
        bf16x8 aw0, aw1;
        aw0[0]=(__bf16)p0[0]; aw0[1]=(__bf16)p0[1]; aw0[2]=(__bf16)p0[2]; aw0[3]=(__bf16)p0[3];
        aw0[4]=(__bf16)p1[0]; aw0[5]=(__bf16)p1[1]; aw0[6]=(__bf16)p1[2]; aw0[7]=(__bf16)p1[3];
        aw1[0]=(__bf16)p2[0]; aw1[1]=(__bf16)p2[1]; aw1[2]=(__bf16)p2[2]; aw1[3]=(__bf16)p2[3];
        aw1[4]=(__bf16)p3[0]; aw1[5]=(__bf16)p3[1]; aw1[6]=(__bf16)p3[2]; aw1[7]=(__bf16)p3[3];
        f32x4 gacc = {0.f, 0.f, 0.f, 0.f};
        gacc = MFMA16(aw0, ae0, gacc);
        gacc = MFMA16(aw1, ae1, gacc);
        ghvp[t * 2 + 0] = pack2(gacc[0] * vacc[0], gacc[1] * vacc[1]);
        ghvp[t * 2 + 1] = pack2(gacc[2] * vacc[2], gacc[3] * vacc[3]);
    }

    // ---------------- W2^T fragments direct from global (A-op: [m=dout][k=j]) ----
    // w2f[c][i] = W2^T[dout = colb+l16][j = c*32+quad*8+i] = W2g[j*64 + dout]
    bf16x8 w2f[8];
#pragma unroll
    for (int c = 0; c < 8; ++c) {
        const float* src = W2g + (c * 32 + quad * 8) * 64 + colb + l16;
        bf16x8 f;
#pragma unroll
        for (int i = 0; i < 8; ++i) f[i] = (__bf16)src[i * 64];
        w2f[c] = f;
    }

    // ---------------- z state + b2 (lane layout: batch=l16, d=colb+quad*4+rg) ----
    f32x4 zv  = *(const f32x4*)(Yg + row * 64 + colb + quad * 4);
    f32x4 bb2 = *(const f32x4*)(b2g + colb + quad * 4);
    const float b1r  = b1g[tid];             // own j = tid
    const float w1tr = W1g[64 * 256 + tid];  // W1 time row

    const float dt = 0.125f;
    u32 kp[6][2];     // k_dz bf16x2: [stage][pair], d = colb + quad*4 + {0..3}
    float lp = 0.f;   // own-j partial of dlogp (batch = l16)

#define KV(s, g) frombits(((g) & 1) ? (kp[s][(g)>>1] >> 16) : (kp[s][(g)>>1] & 0xffffu))

#define S1A(g) (0.2f*KV(0,g))
#define S2A(g) (0.075f*KV(0,g) + 0.225f*KV(1,g))
#define S3A(g) ((44.f/45.f)*KV(0,g) + (-56.f/15.f)*KV(1,g) + (32.f/9.f)*KV(2,g))
#define S4A(g) ((19372.f/6561.f)*KV(0,g) + (-25360.f/2187.f)*KV(1,g) + \
                (64448.f/6561.f)*KV(2,g) + (-212.f/729.f)*KV(3,g))
#define S5A(g) ((9017.f/3168.f)*KV(0,g) + (-355.f/33.f)*KV(1,g) + \
                (46732.f/5247.f)*KV(2,g) + (49.f/176.f)*KV(3,g) + (-5103.f/18656.f)*KV(4,g))
#define CBA(g) ((35.f/384.f)*KV(0,g) + (500.f/1113.f)*KV(2,g) + (125.f/192.f)*KV(3,g) + \
                (-2187.f/6784.f)*KV(4,g) + (11.f/84.f)*KV(5,g))

    // matmul-1 tile: ua init = bw (bias in accumulator); h packed b64 to sH
#define MM1T(t) { \
    f32x4 ua = *(const f32x4*)(sBW + jb + (t)*16 + quad * 4); \
    ua = MFMA16(w1f[(t)*2 + 0], a10, ua); \
    ua = MFMA16(w1f[(t)*2 + 1], a11, ua); \
    float h0 = fast_tanh(ua[0]), h1 = fast_tanh(ua[1]); \
    float h2 = fast_tanh(ua[2]), h3 = fast_tanh(ua[3]); \
    u32 g0 = ghvp[(t)*2 + 0], g1 = ghvp[(t)*2 + 1]; \
    dv += frombits(g0 & 0xffffu) * (1.f - h0*h0); \
    dv += frombits(g0 >> 16)     * (1.f - h1*h1); \
    dv += frombits(g1 & 0xffffu) * (1.f - h2*h2); \
    dv += frombits(g1 >> 16)     * (1.f - h3*h3); \
    bf16x4 hv; hv[0]=(__bf16)h0; hv[1]=(__bf16)h1; hv[2]=(__bf16)h2; hv[3]=(__bf16)h3; \
    *(bf16x4*)(sH + l16 * 264 + jb + (t)*16 + quad * 4) = hv; }

#define MM2C(c) { \
    bf16x8 hf = *(const bf16x8*)(sH + l16 * 264 + (c)*32 + quad * 8); \
    fa = MFMA16(w2f[c], hf, fa); }

#define STAGE(st, CTI, DTB, A0, A1, A2, A3) { \
    const float ti = t0 + (CTI) * dt; \
    { \
        bf16x4 yv; \
        yv[0] = (__bf16)(zv[0] + dt * (A0)); \
        yv[1] = (__bf16)(zv[1] + dt * (A1)); \
        yv[2] = (__bf16)(zv[2] + dt * (A2)); \
        yv[3] = (__bf16)(zv[3] + dt * (A3)); \
        *(bf16x4*)(sY + l16 * 72 + colb + quad * 4) = yv; \
    } \
    sBW[tid] = b1r + ti * w1tr; \
    __syncthreads(); \
    bf16x8 a10 = *(const bf16x8*)(sY + l16 * 72 + quad * 8); \
    bf16x8 a11 = *(const bf16x8*)(sY + l16 * 72 + 32 + quad * 8); \
    float dv = 0.f; \
    MM1T(0) MM1T(1) MM1T(2) MM1T(3) \
    __syncthreads(); \
    f32x4 fa = bb2; \
    MM2C(0) MM2C(1) MM2C(2) MM2C(3) MM2C(4) MM2C(5) MM2C(6) MM2C(7) \
    kp[st][0] = pack2(fa[0], fa[1]); \
    kp[st][1] = pack2(fa[2], fa[3]); \
    dv += __shfl_xor(dv, 16); \
    dv += __shfl_xor(dv, 32); \
    lp -= (DTB) * dv; }

    for (int step = 0; step < 8; ++step) {
        const float t0 = dt * (float)step;
        STAGE(0, 0.f,     dt*(35.f/384.f),    0.f,    0.f,    0.f,    0.f)
        STAGE(1, 0.2f,    0.f,                S1A(0), S1A(1), S1A(2), S1A(3))
        STAGE(2, 0.3f,    dt*(500.f/1113.f),  S2A(0), S2A(1), S2A(2), S2A(3))
        STAGE(3, 0.8f,    dt*(125.f/192.f),   S3A(0), S3A(1), S3A(2), S3A(3))
        STAGE(4, 8.f/9.f, dt*(-2187.f/6784.f),S4A(0), S4A(1), S4A(2), S4A(3))
        STAGE(5, 1.f,     dt*(11.f/84.f),     S5A(0), S5A(1), S5A(2), S5A(3))
        zv[0] += dt * CBA(0);
        zv[1] += dt * CBA(1);
        zv[2] += dt * CBA(2);
        zv[3] += dt * CBA(3);
    }

    // ---------------- epilogue ----------------
    *(f32x4*)(Og + row * 64 + colb + quad * 4) = zv;
    float ss = zv[0]*zv[0] + zv[1]*zv[1] + zv[2]*zv[2] + zv[3]*zv[3];
    ss += __shfl_xor(ss, 16);
    ss += __shfl_xor(ss, 32);
    if (quad == 0) {
        sRedSS[wave * 16 + l16] = ss;
        sRedLP[wave * 16 + l16] = lp;
    }
    __syncthreads();
    if (tid < 16) {
        const float CLOG = -58.8120661f;  // -32*ln(2*pi)
        float sfull = sRedSS[tid] + sRedSS[16 + tid] + sRedSS[32 + tid] + sRedSS[48 + tid];
        float lfull = sRedLP[tid] + sRedLP[16 + tid] + sRedLP[32 + tid] + sRedLP[48 + tid];
        Og[32768 * 64 + blockIdx.x * 16 + tid] = CLOG - 0.5f * sfull - lfull;
    }
}

extern "C" void kernel_launch(void* const* d_in, const int* in_sizes, int n_in,
                              void* d_out, int out_size, void* d_ws, size_t ws_size,
                              hipStream_t stream) {
    const float* Yg  = (const float*)d_in[0];
    const float* Eg  = (const float*)d_in[1];
    const float* W1g = (const float*)d_in[2];  // [65][256]
    const float* b1g = (const float*)d_in[3];
    const float* W2g = (const float*)d_in[4];  // [256][64]
    const float* b2g = (const float*)d_in[5];
    float* Og = (float*)d_out;                 // z (32768*64) then log_px (32768)
    cnf_kernel<<<dim3(2048), dim3(256), 0, stream>>>(Yg, Eg, W1g, b1g, W2g, b2g, Og);
}

// Round 2
// 627.544 us; speedup vs baseline: 1.8306x; 1.8306x over previous
//
#include <hip/hip_runtime.h>

// CNF forward: 8 fixed dopri5 steps x 6 stages, rows independent.
// R7: R6's structure (256-thr blocks, 12 KB LDS, all weight frags in regs,
// operand-swap transpose) was correct, but __launch_bounds__(256,5) forced
// the allocator into the <=64-VGPR occupancy tier (reported 48 VGPRs) ->
// w1f/w2f spilled to scratch -> 3.1 GB/dispatch HBM traffic, 4x regression.
// Fix: pin to the tier that fits the ~100-VGPR working set:
// __launch_bounds__(256,4) -> 128-VGPR cap, 4 waves/EU = 16 waves/CU
// (2x R5's occupancy, zero spill).

typedef __bf16 bf16x8 __attribute__((ext_vector_type(8)));
typedef __bf16 bf16x4 __attribute__((ext_vector_type(4)));
typedef float  f32x4  __attribute__((ext_vector_type(4)));
typedef unsigned int u32;

#define MFMA16(a, b, c) __builtin_amdgcn_mfma_f32_16x16x32_bf16((a), (b), (c), 0, 0, 0)

__device__ __forceinline__ u32 bfbits(float x) {
    __bf16 b = (__bf16)x;                      // RNE fp32->bf16
    return (u32)__builtin_bit_cast(unsigned short, b);
}
__device__ __forceinline__ float frombits(u32 u16) {
    return __builtin_bit_cast(float, u16 << 16);
}
__device__ __forceinline__ u32 pack2(float lo, float hi) {
    return bfbits(lo) | (bfbits(hi) << 16);
}
__device__ __forceinline__ float fast_tanh(float x) {
    float e = __expf(2.0f * x);
    return 1.0f - 2.0f * __builtin_amdgcn_rcpf(e + 1.0f);
}

extern "C" __global__ void __launch_bounds__(256, 4)
cnf_kernel(const float* __restrict__ Yg, const float* __restrict__ Eg,
           const float* __restrict__ W1g, const float* __restrict__ b1g,
           const float* __restrict__ W2g, const float* __restrict__ b2g,
           float* __restrict__ Og)
{
    // ---- LDS (12 KB) ----
    __shared__ __align__(16) __bf16 sY[16 * 72];    // y buf [batch][d]
    __shared__ __align__(16) __bf16 sH[16 * 264];   // h buf [batch][j]
    __shared__ float sBW[256];                      // per-stage b1 + t*W1_t
    __shared__ float sRedSS[64], sRedLP[64];

    const int tid  = threadIdx.x;
    const int wave = tid >> 6;        // 0..3: wave's slot within the group
    const int lane = tid & 63;
    const int quad = lane >> 4;
    const int l16  = lane & 15;
    const int colb = wave * 16;       // own output-col tile base
    const int jb   = wave * 64;       // own hidden-j base (4 tiles of 16)
    const int row  = blockIdx.x * 16 + l16;   // this lane's batch row

    // ---------------- e fragments direct from global ----------------
    // ae: lane (l16=batch, quad) holds e[row][d = quad*8 + i] (+32 for ae1)
    bf16x8 ae0, ae1;
    {
        f32x4 ea = *(const f32x4*)(Eg + row * 64 + quad * 8);
        f32x4 eb = *(const f32x4*)(Eg + row * 64 + quad * 8 + 4);
        f32x4 ec = *(const f32x4*)(Eg + row * 64 + 32 + quad * 8);
        f32x4 ed = *(const f32x4*)(Eg + row * 64 + 32 + quad * 8 + 4);
        ae0[0]=(__bf16)ea[0]; ae0[1]=(__bf16)ea[1]; ae0[2]=(__bf16)ea[2]; ae0[3]=(__bf16)ea[3];
        ae0[4]=(__bf16)eb[0]; ae0[5]=(__bf16)eb[1]; ae0[6]=(__bf16)eb[2]; ae0[7]=(__bf16)eb[3];
        ae1[0]=(__bf16)ec[0]; ae1[1]=(__bf16)ec[1]; ae1[2]=(__bf16)ec[2]; ae1[3]=(__bf16)ec[3];
        ae1[4]=(__bf16)ed[0]; ae1[5]=(__bf16)ed[1]; ae1[6]=(__bf16)ed[2]; ae1[7]=(__bf16)ed[3];
    }

    // ---------------- W1 fragments direct from global (A-op: [m=j][k=d]) ----
    // w1f[t*2+h][i] = W1^T[j = jb+t*16+l16][d = h*32+quad*8+i] = W1g[d*256 + j]
    bf16x8 w1f[8];
#pragma unroll
    for (int t = 0; t < 4; ++t) {
#pragma unroll
        for (int h = 0; h < 2; ++h) {
            const float* src = W1g + (h * 32 + quad * 8) * 256 + jb + t * 16 + l16;
            bf16x8 f;
#pragma unroll
            for (int i = 0; i < 8; ++i) f[i] = (__bf16)src[i * 256];
            w1f[t * 2 + h] = f;
        }
    }

    // ---------------- ghv[j][batch] = gh0 .* v, layout j=quad*4+rg, batch=l16 ----
    // v^T = (e@W1a)^T via operand swap: A=W1a^T[m=j][k=d], B=e^T[k=d][n=b]
    //   -> C[j=quad*4+rg][b=l16]  (no transpose scratch needed)
    // gh0^T = W2@e^T: A=W2[m=j][k=d] (contiguous rows of W2g), B=e^T
    u32 ghvp[8];   // [tile*2 + pair], bf16x2 packed
#pragma unroll
    for (int t = 0; t < 4; ++t) {
        f32x4 vacc = {0.f, 0.f, 0.f, 0.f};
        vacc = MFMA16(w1f[t * 2 + 0], ae0, vacc);
        vacc = MFMA16(w1f[t * 2 + 1], ae1, vacc);
        const float* wr = W2g + (jb + t * 16 + l16) * 64;
        f32x4 p0 = *(const f32x4*)(wr + quad * 8);
        f32x4 p1 = *(const f32x4*)(wr + quad * 8 + 4);
        f32x4 p2 = *(const f32x4*)(wr + 32 + quad * 8);
        f32x4 p3 = *(const f32x4*)(wr + 32 + quad * 8 + 4);
        bf16x8 aw0, aw1;
        aw0[0]=(__bf16)p0[0]; aw0[1]=(__bf16)p0[1]; aw0[2]=(__bf16)p0[2]; aw0[3]=(__bf16)p0[3];
        aw0[4]=(__bf16)p1[0]; aw0[5]=(__bf16)p1[1]; aw0[6]=(__bf16)p1[2]; aw0[7]=(__bf16)p1[3];
        aw1[0]=(__bf16)p2[0]; aw1[1]=(__bf16)p2[1]; aw1[2]=(__bf16)p2[2]; aw1[3]=(__bf16)p2[3];
        aw1[4]=(__bf16)p3[0]; aw1[5]=(__bf16)p3[1]; aw1[6]=(__bf16)p3[2]; aw1[7]=(__bf16)p3[3];
        f32x4 gacc = {0.f, 0.f, 0.f, 0.f};
        gacc = MFMA16(aw0, ae0, gacc);
        gacc = MFMA16(aw1, ae1, gacc);
        ghvp[t * 2 + 0] = pack2(gacc[0] * vacc[0], gacc[1] * vacc[1]);
        ghvp[t * 2 + 1] = pack2(gacc[2] * vacc[2], gacc[3] * vacc[3]);
    }

    // ---------------- W2^T fragments direct from global (A-op: [m=dout][k=j]) ----
    // w2f[c][i] = W2^T[dout = colb+l16][j = c*32+quad*8+i] = W2g[j*64 + dout]
    bf16x8 w2f[8];
#pragma unroll
    for (int c = 0; c < 8; ++c) {
        const float* src = W2g + (c * 32 + quad * 8) * 64 + colb + l16;
        bf16x8 f;
#pragma unroll
        for (int i = 0; i < 8; ++i) f[i] = (__bf16)src[i * 64];
        w2f[c] = f;
    }

    // ---------------- z state + b2 (lane layout: batch=l16, d=colb+quad*4+rg) ----
    f32x4 zv  = *(const f32x4*)(Yg + row * 64 + colb + quad * 4);
    f32x4 bb2 = *(const f32x4*)(b2g + colb + quad * 4);
    const float b1r  = b1g[tid];             // own j = tid
    const float w1tr = W1g[64 * 256 + tid];  // W1 time row

    const float dt = 0.125f;
    u32 kp[6][2];     // k_dz bf16x2: [stage][pair], d = colb + quad*4 + {0..3}
    float lp = 0.f;   // own-j partial of dlogp (batch = l16)

#define KV(s, g) frombits(((g) & 1) ? (kp[s][(g)>>1] >> 16) : (kp[s][(g)>>1] & 0xffffu))

#define S1A(g) (0.2f*KV(0,g))
#define S2A(g) (0.075f*KV(0,g) + 0.225f*KV(1,g))
#define S3A(g) ((44.f/45.f)*KV(0,g) + (-56.f/15.f)*KV(1,g) + (32.f/9.f)*KV(2,g))
#define S4A(g) ((19372.f/6561.f)*KV(0,g) + (-25360.f/2187.f)*KV(1,g) + \
                (64448.f/6561.f)*KV(2,g) + (-212.f/729.f)*KV(3,g))
#define S5A(g) ((9017.f/3168.f)*KV(0,g) + (-355.f/33.f)*KV(1,g) + \
                (46732.f/5247.f)*KV(2,g) + (49.f/176.f)*KV(3,g) + (-5103.f/18656.f)*KV(4,g))
#define CBA(g) ((35.f/384.f)*KV(0,g) + (500.f/1113.f)*KV(2,g) + (125.f/192.f)*KV(3,g) + \
                (-2187.f/6784.f)*KV(4,g) + (11.f/84.f)*KV(5,g))

    // matmul-1 tile: ua init = bw (bias in accumulator); h packed b64 to sH
#define MM1T(t) { \
    f32x4 ua = *(const f32x4*)(sBW + jb + (t)*16 + quad * 4); \
    ua = MFMA16(w1f[(t)*2 + 0], a10, ua); \
    ua = MFMA16(w1f[(t)*2 + 1], a11, ua); \
    float h0 = fast_tanh(ua[0]), h1 = fast_tanh(ua[1]); \
    float h2 = fast_tanh(ua[2]), h3 = fast_tanh(ua[3]); \
    u32 g0 = ghvp[(t)*2 + 0], g1 = ghvp[(t)*2 + 1]; \
    dv += frombits(g0 & 0xffffu) * (1.f - h0*h0); \
    dv += frombits(g0 >> 16)     * (1.f - h1*h1); \
    dv += frombits(g1 & 0xffffu) * (1.f - h2*h2); \
    dv += frombits(g1 >> 16)     * (1.f - h3*h3); \
    bf16x4 hv; hv[0]=(__bf16)h0; hv[1]=(__bf16)h1; hv[2]=(__bf16)h2; hv[3]=(__bf16)h3; \
    *(bf16x4*)(sH + l16 * 264 + jb + (t)*16 + quad * 4) = hv; }

#define MM2C(c) { \
    bf16x8 hf = *(const bf16x8*)(sH + l16 * 264 + (c)*32 + quad * 8); \
    fa = MFMA16(w2f[c], hf, fa); }

#define STAGE(st, CTI, DTB, A0, A1, A2, A3) { \
    const float ti = t0 + (CTI) * dt; \
    { \
        bf16x4 yv; \
        yv[0] = (__bf16)(zv[0] + dt * (A0)); \
        yv[1] = (__bf16)(zv[1] + dt * (A1)); \
        yv[2] = (__bf16)(zv[2] + dt * (A2)); \
        yv[3] = (__bf16)(zv[3] + dt * (A3)); \
        *(bf16x4*)(sY + l16 * 72 + colb + quad * 4) = yv; \
    } \
    sBW[tid] = b1r + ti * w1tr; \
    __syncthreads(); \
    bf16x8 a10 = *(const bf16x8*)(sY + l16 * 72 + quad * 8); \
    bf16x8 a11 = *(const bf16x8*)(sY + l16 * 72 + 32 + quad * 8); \
    float dv = 0.f; \
    MM1T(0) MM1T(1) MM1T(2) MM1T(3) \
    __syncthreads(); \
    f32x4 fa = bb2; \
    MM2C(0) MM2C(1) MM2C(2) MM2C(3) MM2C(4) MM2C(5) MM2C(6) MM2C(7) \
    kp[st][0] = pack2(fa[0], fa[1]); \
    kp[st][1] = pack2(fa[2], fa[3]); \
    dv += __shfl_xor(dv, 16); \
    dv += __shfl_xor(dv, 32); \
    lp -= (DTB) * dv; }

    for (int step = 0; step < 8; ++step) {
        const float t0 = dt * (float)step;
        STAGE(0, 0.f,     dt*(35.f/384.f),    0.f,    0.f,    0.f,    0.f)
        STAGE(1, 0.2f,    0.f,                S1A(0), S1A(1), S1A(2), S1A(3))
        STAGE(2, 0.3f,    dt*(500.f/1113.f),  S2A(0), S2A(1), S2A(2), S2A(3))
        STAGE(3, 0.8f,    dt*(125.f/192.f),   S3A(0), S3A(1), S3A(2), S3A(3))
        STAGE(4, 8.f/9.f, dt*(-2187.f/6784.f),S4A(0), S4A(1), S4A(2), S4A(3))
        STAGE(5, 1.f,     dt*(11.f/84.f),     S5A(0), S5A(1), S5A(2), S5A(3))
        zv[0] += dt * CBA(0);
        zv[1] += dt * CBA(1);
        zv[2] += dt * CBA(2);
        zv[3] += dt * CBA(3);
    }

    // ---------------- epilogue ----------------
    *(f32x4*)(Og + row * 64 + colb + quad * 4) = zv;
    float ss = zv[0]*zv[0] + zv[1]*zv[1] + zv[2]*zv[2] + zv[3]*zv[3];
    ss += __shfl_xor(ss, 16);
    ss += __shfl_xor(ss, 32);
    if (quad == 0) {
        sRedSS[wave * 16 + l16] = ss;
        sRedLP[wave * 16 + l16] = lp;
    }
    __syncthreads();
    if (tid < 16) {
        const float CLOG = -58.8120661f;  // -32*ln(2*pi)
        float sfull = sRedSS[tid] + sRedSS[16 + tid] + sRedSS[32 + tid] + sRedSS[48 + tid];
        float lfull = sRedLP[tid] + sRedLP[16 + tid] + sRedLP[32 + tid] + sRedLP[48 + tid];
        Og[32768 * 64 + blockIdx.x * 16 + tid] = CLOG - 0.5f * sfull - lfull;
    }
}

extern "C" void kernel_launch(void* const* d_in, const int* in_sizes, int n_in,
                              void* d_out, int out_size, void* d_ws, size_t ws_size,
                              hipStream_t stream) {
    const float* Yg  = (const float*)d_in[0];
    const float* Eg  = (const float*)d_in[1];
    const float* W1g = (const float*)d_in[2];  // [65][256]
    const float* b1g = (const float*)d_in[3];
    const float* W2g = (const float*)d_in[4];  // [256][64]
    const float* b2g = (const float*)d_in[5];
    float* Og = (float*)d_out;                 // z (32768*64) then log_px (32768)
    cnf_kernel<<<dim3(2048), dim3(256), 0, stream>>>(Yg, Eg, W1g, b1g, W2g, b2g, Og);
}

// Round 3
// 617.925 us; speedup vs baseline: 1.8591x; 1.0156x over previous
//
#include <hip/hip_runtime.h>

// CNF forward: 8 fixed dopri5 steps x 6 stages, rows independent.
// R8: R7 still spilled -- gfx950 backend splits the unified 128-VGPR budget
// (launch_bounds(256,4)) into 64 arch + 64 acc via accum_offset, and did NOT
// place the 64 regs of weight fragments in the acc half -> weights thrashed
// scratch (1.5 GB FETCH/dispatch; dur == spill-bytes/3.5TBs exactly).
// Fix: weight frags feed ONLY MFMA (A/B operands may be AGPRs on gfx950),
// so pin w1f/w2f into the AGPR half with empty asm "+a" class hints.
// Arch half then holds ghvp(8)+kp(12)+zv(4)+scalars+temps ~= 60 <= 64; bb2
// moved to LDS (sB2) to make room. Total 128 -> 4 waves/EU, zero spill.

typedef __bf16 bf16x8 __attribute__((ext_vector_type(8)));
typedef __bf16 bf16x4 __attribute__((ext_vector_type(4)));
typedef float  f32x4  __attribute__((ext_vector_type(4)));
typedef unsigned int u32;
typedef u32 u32x4 __attribute__((ext_vector_type(4)));

#define MFMA16(a, b, c) __builtin_amdgcn_mfma_f32_16x16x32_bf16((a), (b), (c), 0, 0, 0)

__device__ __forceinline__ u32 bfbits(float x) {
    __bf16 b = (__bf16)x;                      // RNE fp32->bf16
    return (u32)__builtin_bit_cast(unsigned short, b);
}
__device__ __forceinline__ float frombits(u32 u16) {
    return __builtin_bit_cast(float, u16 << 16);
}
__device__ __forceinline__ u32 pack2(float lo, float hi) {
    return bfbits(lo) | (bfbits(hi) << 16);
}
__device__ __forceinline__ float fast_tanh(float x) {
    float e = __expf(2.0f * x);
    return 1.0f - 2.0f * __builtin_amdgcn_rcpf(e + 1.0f);
}
// Pin a 128-bit fragment into the AGPR half of the unified file.
__device__ __forceinline__ bf16x8 to_agpr(bf16x8 v) {
    u32x4 t = __builtin_bit_cast(u32x4, v);
    asm volatile("" : "+a"(t));
    return __builtin_bit_cast(bf16x8, t);
}

extern "C" __global__ void __launch_bounds__(256, 4)
cnf_kernel(const float* __restrict__ Yg, const float* __restrict__ Eg,
           const float* __restrict__ W1g, const float* __restrict__ b1g,
           const float* __restrict__ W2g, const float* __restrict__ b2g,
           float* __restrict__ Og)
{
    // ---- LDS (~12.5 KB) ----
    __shared__ __align__(16) __bf16 sY[16 * 72];    // y buf [batch][d]
    __shared__ __align__(16) __bf16 sH[16 * 264];   // h buf [batch][j]
    __shared__ float sBW[256];                      // per-stage b1 + t*W1_t
    __shared__ __align__(16) float sB2[64];         // b2 (keeps bb2 out of arch regs)
    __shared__ float sRedSS[64], sRedLP[64];

    const int tid  = threadIdx.x;
    const int wave = tid >> 6;        // 0..3: wave's slot within the group
    const int lane = tid & 63;
    const int quad = lane >> 4;
    const int l16  = lane & 15;
    const int colb = wave * 16;       // own output-col tile base
    const int jb   = wave * 64;       // own hidden-j base (4 tiles of 16)
    const int row  = blockIdx.x * 16 + l16;   // this lane's batch row

    if (tid < 64) sB2[tid] = b2g[tid];

    // ---------------- e fragments direct from global ----------------
    // ae: lane (l16=batch, quad) holds e[row][d = quad*8 + i] (+32 for ae1)
    bf16x8 ae0, ae1;
    {
        f32x4 ea = *(const f32x4*)(Eg + row * 64 + quad * 8);
        f32x4 eb = *(const f32x4*)(Eg + row * 64 + quad * 8 + 4);
        f32x4 ec = *(const f32x4*)(Eg + row * 64 + 32 + quad * 8);
        f32x4 ed = *(const f32x4*)(Eg + row * 64 + 32 + quad * 8 + 4);
        ae0[0]=(__bf16)ea[0]; ae0[1]=(__bf16)ea[1]; ae0[2]=(__bf16)ea[2]; ae0[3]=(__bf16)ea[3];
        ae0[4]=(__bf16)eb[0]; ae0[5]=(__bf16)eb[1]; ae0[6]=(__bf16)eb[2]; ae0[7]=(__bf16)eb[3];
        ae1[0]=(__bf16)ec[0]; ae1[1]=(__bf16)ec[1]; ae1[2]=(__bf16)ec[2]; ae1[3]=(__bf16)ec[3];
        ae1[4]=(__bf16)ed[0]; ae1[5]=(__bf16)ed[1]; ae1[6]=(__bf16)ed[2]; ae1[7]=(__bf16)ed[3];
    }

    // ---------------- W1 fragments direct from global (A-op: [m=j][k=d]) ----
    // w1f[t*2+h][i] = W1^T[j = jb+t*16+l16][d = h*32+quad*8+i] = W1g[d*256 + j]
    bf16x8 w1f[8];
#pragma unroll
    for (int t = 0; t < 4; ++t) {
#pragma unroll
        for (int h = 0; h < 2; ++h) {
            const float* src = W1g + (h * 32 + quad * 8) * 256 + jb + t * 16 + l16;
            bf16x8 f;
#pragma unroll
            for (int i = 0; i < 8; ++i) f[i] = (__bf16)src[i * 256];
            w1f[t * 2 + h] = f;
        }
    }
#pragma unroll
    for (int i = 0; i < 8; ++i) w1f[i] = to_agpr(w1f[i]);   // park in AGPR half

    // ---------------- ghv[j][batch] = gh0 .* v, layout j=quad*4+rg, batch=l16 ----
    // v^T = (e@W1a)^T via operand swap: A=W1a^T[m=j][k=d], B=e^T[k=d][n=b]
    //   -> C[j=quad*4+rg][b=l16]  (no transpose scratch needed)
    // gh0^T = W2@e^T: A=W2[m=j][k=d] (contiguous rows of W2g), B=e^T
    u32 ghvp[8];   // [tile*2 + pair], bf16x2 packed
#pragma unroll
    for (int t = 0; t < 4; ++t) {
        f32x4 vacc = {0.f, 0.f, 0.f, 0.f};
        vacc = MFMA16(w1f[t * 2 + 0], ae0, vacc);
        vacc = MFMA16(w1f[t * 2 + 1], ae1, vacc);
        const float* wr = W2g + (jb + t * 16 + l16) * 64;
        f32x4 p0 = *(const f32x4*)(wr + quad * 8);
        f32x4 p1 = *(const f32x4*)(wr + quad * 8 + 4);
        f32x4 p2 = *(const f32x4*)(wr + 32 + quad * 8);
        f32x4 p3 = *(const f32x4*)(wr + 32 + quad * 8 + 4);
        bf16x8 aw0, aw1;
        aw0[0]=(__bf16)p0[0]; aw0[1]=(__bf16)p0[1]; aw0[2]=(__bf16)p0[2]; aw0[3]=(__bf16)p0[3];
        aw0[4]=(__bf16)p1[0]; aw0[5]=(__bf16)p1[1]; aw0[6]=(__bf16)p1[2]; aw0[7]=(__bf16)p1[3];
        aw1[0]=(__bf16)p2[0]; aw1[1]=(__bf16)p2[1]; aw1[2]=(__bf16)p2[2]; aw1[3]=(__bf16)p2[3];
        aw1[4]=(__bf16)p3[0]; aw1[5]=(__bf16)p3[1]; aw1[6]=(__bf16)p3[2]; aw1[7]=(__bf16)p3[3];
        f32x4 gacc = {0.f, 0.f, 0.f, 0.f};
        gacc = MFMA16(aw0, ae0, gacc);
        gacc = MFMA16(aw1, ae1, gacc);
        ghvp[t * 2 + 0] = pack2(gacc[0] * vacc[0], gacc[1] * vacc[1]);
        ghvp[t * 2 + 1] = pack2(gacc[2] * vacc[2], gacc[3] * vacc[3]);
    }

    // ---------------- W2^T fragments direct from global (A-op: [m=dout][k=j]) ----
    // w2f[c][i] = W2^T[dout = colb+l16][j = c*32+quad*8+i] = W2g[j*64 + dout]
    bf16x8 w2f[8];
#pragma unroll
    for (int c = 0; c < 8; ++c) {
        const float* src = W2g + (c * 32 + quad * 8) * 64 + colb + l16;
        bf16x8 f;
#pragma unroll
        for (int i = 0; i < 8; ++i) f[i] = (__bf16)src[i * 64];
        w2f[c] = f;
    }
#pragma unroll
    for (int i = 0; i < 8; ++i) w2f[i] = to_agpr(w2f[i]);   // park in AGPR half

    // ---------------- z state (lane layout: batch=l16, d=colb+quad*4+rg) ----
    f32x4 zv = *(const f32x4*)(Yg + row * 64 + colb + quad * 4);
    const float b1r  = b1g[tid];             // own j = tid
    const float w1tr = W1g[64 * 256 + tid];  // W1 time row

    const float dt = 0.125f;
    u32 kp[6][2];     // k_dz bf16x2: [stage][pair], d = colb + quad*4 + {0..3}
    float lp = 0.f;   // own-j partial of dlogp (batch = l16)

#define KV(s, g) frombits(((g) & 1) ? (kp[s][(g)>>1] >> 16) : (kp[s][(g)>>1] & 0xffffu))

#define S1A(g) (0.2f*KV(0,g))
#define S2A(g) (0.075f*KV(0,g) + 0.225f*KV(1,g))
#define S3A(g) ((44.f/45.f)*KV(0,g) + (-56.f/15.f)*KV(1,g) + (32.f/9.f)*KV(2,g))
#define S4A(g) ((19372.f/6561.f)*KV(0,g) + (-25360.f/2187.f)*KV(1,g) + \
                (64448.f/6561.f)*KV(2,g) + (-212.f/729.f)*KV(3,g))
#define S5A(g) ((9017.f/3168.f)*KV(0,g) + (-355.f/33.f)*KV(1,g) + \
                (46732.f/5247.f)*KV(2,g) + (49.f/176.f)*KV(3,g) + (-5103.f/18656.f)*KV(4,g))
#define CBA(g) ((35.f/384.f)*KV(0,g) + (500.f/1113.f)*KV(2,g) + (125.f/192.f)*KV(3,g) + \
                (-2187.f/6784.f)*KV(4,g) + (11.f/84.f)*KV(5,g))

    // matmul-1 tile: ua init = bw (bias in accumulator); h packed b64 to sH
#define MM1T(t) { \
    f32x4 ua = *(const f32x4*)(sBW + jb + (t)*16 + quad * 4); \
    ua = MFMA16(w1f[(t)*2 + 0], a10, ua); \
    ua = MFMA16(w1f[(t)*2 + 1], a11, ua); \
    float h0 = fast_tanh(ua[0]), h1 = fast_tanh(ua[1]); \
    float h2 = fast_tanh(ua[2]), h3 = fast_tanh(ua[3]); \
    u32 g0 = ghvp[(t)*2 + 0], g1 = ghvp[(t)*2 + 1]; \
    dv += frombits(g0 & 0xffffu) * (1.f - h0*h0); \
    dv += frombits(g0 >> 16)     * (1.f - h1*h1); \
    dv += frombits(g1 & 0xffffu) * (1.f - h2*h2); \
    dv += frombits(g1 >> 16)     * (1.f - h3*h3); \
    bf16x4 hv; hv[0]=(__bf16)h0; hv[1]=(__bf16)h1; hv[2]=(__bf16)h2; hv[3]=(__bf16)h3; \
    *(bf16x4*)(sH + l16 * 264 + jb + (t)*16 + quad * 4) = hv; }

#define MM2C(c) { \
    bf16x8 hf = *(const bf16x8*)(sH + l16 * 264 + (c)*32 + quad * 8); \
    fa = MFMA16(w2f[c], hf, fa); }

#define STAGE(st, CTI, DTB, A0, A1, A2, A3) { \
    const float ti = t0 + (CTI) * dt; \
    { \
        bf16x4 yv; \
        yv[0] = (__bf16)(zv[0] + dt * (A0)); \
        yv[1] = (__bf16)(zv[1] + dt * (A1)); \
        yv[2] = (__bf16)(zv[2] + dt * (A2)); \
        yv[3] = (__bf16)(zv[3] + dt * (A3)); \
        *(bf16x4*)(sY + l16 * 72 + colb + quad * 4) = yv; \
    } \
    sBW[tid] = b1r + ti * w1tr; \
    __syncthreads(); \
    bf16x8 a10 = *(const bf16x8*)(sY + l16 * 72 + quad * 8); \
    bf16x8 a11 = *(const bf16x8*)(sY + l16 * 72 + 32 + quad * 8); \
    float dv = 0.f; \
    MM1T(0) MM1T(1) MM1T(2) MM1T(3) \
    __syncthreads(); \
    f32x4 fa = *(const f32x4*)(sB2 + colb + quad * 4); \
    MM2C(0) MM2C(1) MM2C(2) MM2C(3) MM2C(4) MM2C(5) MM2C(6) MM2C(7) \
    kp[st][0] = pack2(fa[0], fa[1]); \
    kp[st][1] = pack2(fa[2], fa[3]); \
    dv += __shfl_xor(dv, 16); \
    dv += __shfl_xor(dv, 32); \
    lp -= (DTB) * dv; }

    for (int step = 0; step < 8; ++step) {
        const float t0 = dt * (float)step;
        STAGE(0, 0.f,     dt*(35.f/384.f),    0.f,    0.f,    0.f,    0.f)
        STAGE(1, 0.2f,    0.f,                S1A(0), S1A(1), S1A(2), S1A(3))
        STAGE(2, 0.3f,    dt*(500.f/1113.f),  S2A(0), S2A(1), S2A(2), S2A(3))
        STAGE(3, 0.8f,    dt*(125.f/192.f),   S3A(0), S3A(1), S3A(2), S3A(3))
        STAGE(4, 8.f/9.f, dt*(-2187.f/6784.f),S4A(0), S4A(1), S4A(2), S4A(3))
        STAGE(5, 1.f,     dt*(11.f/84.f),     S5A(0), S5A(1), S5A(2), S5A(3))
        zv[0] += dt * CBA(0);
        zv[1] += dt * CBA(1);
        zv[2] += dt * CBA(2);
        zv[3] += dt * CBA(3);
    }

    // ---------------- epilogue ----------------
    *(f32x4*)(Og + row * 64 + colb + quad * 4) = zv;
    float ss = zv[0]*zv[0] + zv[1]*zv[1] + zv[2]*zv[2] + zv[3]*zv[3];
    ss += __shfl_xor(ss, 16);
    ss += __shfl_xor(ss, 32);
    if (quad == 0) {
        sRedSS[wave * 16 + l16] = ss;
        sRedLP[wave * 16 + l16] = lp;
    }
    __syncthreads();
    if (tid < 16) {
        const float CLOG = -58.8120661f;  // -32*ln(2*pi)
        float sfull = sRedSS[tid] + sRedSS[16 + tid] + sRedSS[32 + tid] + sRedSS[48 + tid];
        float lfull = sRedLP[tid] + sRedLP[16 + tid] + sRedLP[32 + tid] + sRedLP[48 + tid];
        Og[32768 * 64 + blockIdx.x * 16 + tid] = CLOG - 0.5f * sfull - lfull;
    }
}

extern "C" void kernel_launch(void* const* d_in, const int* in_sizes, int n_in,
                              void* d_out, int out_size, void* d_ws, size_t ws_size,
                              hipStream_t stream) {
    const float* Yg  = (const float*)d_in[0];
    const float* Eg  = (const float*)d_in[1];
    const float* W1g = (const float*)d_in[2];  // [65][256]
    const float* b1g = (const float*)d_in[3];
    const float* W2g = (const float*)d_in[4];  // [256][64]
    const float* b2g = (const float*)d_in[5];
    float* Og = (float*)d_out;                 // z (32768*64) then log_px (32768)
    cnf_kernel<<<dim3(2048), dim3(256), 0, stream>>>(Yg, Eg, W1g, b1g, W2g, b2g, Og);
}

// Round 4
// 340.536 us; speedup vs baseline: 3.3735x; 1.8146x over previous
//
#include <hip/hip_runtime.h>

// CNF forward: 8 fixed dopri5 steps x 6 stages, rows independent.
// R9: the R6-R8 spills were a CAPACITY bug, not a placement bug. The loop's
// natural working set is ~152 regs/wave (64 weight frags in the AGPR half +
// ~88 arch -- R5's reported 88 was arch-only). Bounds of 4-5 waves/EU give
// 128/96-reg budgets < 152 -> forced spill (1.5 GB scratch traffic/dispatch,
// dur == spill-bytes / 3.5 TB/s). 3 waves/EU gives 170 >= 152: zero spill,
// 12 waves/CU (1.5x R5's 8). AGPR asm pins dropped -- with a sufficient
// budget the allocator splits correctly on its own (it did in R5).

typedef __bf16 bf16x8 __attribute__((ext_vector_type(8)));
typedef __bf16 bf16x4 __attribute__((ext_vector_type(4)));
typedef float  f32x4  __attribute__((ext_vector_type(4)));
typedef unsigned int u32;

#define MFMA16(a, b, c) __builtin_amdgcn_mfma_f32_16x16x32_bf16((a), (b), (c), 0, 0, 0)

__device__ __forceinline__ u32 bfbits(float x) {
    __bf16 b = (__bf16)x;                      // RNE fp32->bf16
    return (u32)__builtin_bit_cast(unsigned short, b);
}
__device__ __forceinline__ float frombits(u32 u16) {
    return __builtin_bit_cast(float, u16 << 16);
}
__device__ __forceinline__ u32 pack2(float lo, float hi) {
    return bfbits(lo) | (bfbits(hi) << 16);
}
__device__ __forceinline__ float fast_tanh(float x) {
    float e = __expf(2.0f * x);
    return 1.0f - 2.0f * __builtin_amdgcn_rcpf(e + 1.0f);
}

extern "C" __global__ void __launch_bounds__(256, 3)
cnf_kernel(const float* __restrict__ Yg, const float* __restrict__ Eg,
           const float* __restrict__ W1g, const float* __restrict__ b1g,
           const float* __restrict__ W2g, const float* __restrict__ b2g,
           float* __restrict__ Og)
{
    // ---- LDS (~12.5 KB) ----
    __shared__ __align__(16) __bf16 sY[16 * 72];    // y buf [batch][d]
    __shared__ __align__(16) __bf16 sH[16 * 264];   // h buf [batch][j]
    __shared__ float sBW[256];                      // per-stage b1 + t*W1_t
    __shared__ __align__(16) float sB2[64];         // b2 (keeps bb2 out of arch regs)
    __shared__ float sRedSS[64], sRedLP[64];

    const int tid  = threadIdx.x;
    const int wave = tid >> 6;        // 0..3: wave's slot within the group
    const int lane = tid & 63;
    const int quad = lane >> 4;
    const int l16  = lane & 15;
    const int colb = wave * 16;       // own output-col tile base
    const int jb   = wave * 64;       // own hidden-j base (4 tiles of 16)
    const int row  = blockIdx.x * 16 + l16;   // this lane's batch row

    if (tid < 64) sB2[tid] = b2g[tid];

    // ---------------- e fragments direct from global ----------------
    // ae: lane (l16=batch, quad) holds e[row][d = quad*8 + i] (+32 for ae1)
    bf16x8 ae0, ae1;
    {
        f32x4 ea = *(const f32x4*)(Eg + row * 64 + quad * 8);
        f32x4 eb = *(const f32x4*)(Eg + row * 64 + quad * 8 + 4);
        f32x4 ec = *(const f32x4*)(Eg + row * 64 + 32 + quad * 8);
        f32x4 ed = *(const f32x4*)(Eg + row * 64 + 32 + quad * 8 + 4);
        ae0[0]=(__bf16)ea[0]; ae0[1]=(__bf16)ea[1]; ae0[2]=(__bf16)ea[2]; ae0[3]=(__bf16)ea[3];
        ae0[4]=(__bf16)eb[0]; ae0[5]=(__bf16)eb[1]; ae0[6]=(__bf16)eb[2]; ae0[7]=(__bf16)eb[3];
        ae1[0]=(__bf16)ec[0]; ae1[1]=(__bf16)ec[1]; ae1[2]=(__bf16)ec[2]; ae1[3]=(__bf16)ec[3];
        ae1[4]=(__bf16)ed[0]; ae1[5]=(__bf16)ed[1]; ae1[6]=(__bf16)ed[2]; ae1[7]=(__bf16)ed[3];
    }

    // ---------------- W1 fragments direct from global (A-op: [m=j][k=d]) ----
    // w1f[t*2+h][i] = W1^T[j = jb+t*16+l16][d = h*32+quad*8+i] = W1g[d*256 + j]
    bf16x8 w1f[8];
#pragma unroll
    for (int t = 0; t < 4; ++t) {
#pragma unroll
        for (int h = 0; h < 2; ++h) {
            const float* src = W1g + (h * 32 + quad * 8) * 256 + jb + t * 16 + l16;
            bf16x8 f;
#pragma unroll
            for (int i = 0; i < 8; ++i) f[i] = (__bf16)src[i * 256];
            w1f[t * 2 + h] = f;
        }
    }

    // ---------------- ghv[j][batch] = gh0 .* v, layout j=quad*4+rg, batch=l16 ----
    // v^T = (e@W1a)^T via operand swap: A=W1a^T[m=j][k=d], B=e^T[k=d][n=b]
    //   -> C[j=quad*4+rg][b=l16]  (no transpose scratch needed)
    // gh0^T = W2@e^T: A=W2[m=j][k=d] (contiguous rows of W2g), B=e^T
    u32 ghvp[8];   // [tile*2 + pair], bf16x2 packed
#pragma unroll
    for (int t = 0; t < 4; ++t) {
        f32x4 vacc = {0.f, 0.f, 0.f, 0.f};
        vacc = MFMA16(w1f[t * 2 + 0], ae0, vacc);
        vacc = MFMA16(w1f[t * 2 + 1], ae1, vacc);
        const float* wr = W2g + (jb + t * 16 + l16) * 64;
        f32x4 p0 = *(const f32x4*)(wr + quad * 8);
        f32x4 p1 = *(const f32x4*)(wr + quad * 8 + 4);
        f32x4 p2 = *(const f32x4*)(wr + 32 + quad * 8);
        f32x4 p3 = *(const f32x4*)(wr + 32 + quad * 8 + 4);
        bf16x8 aw0, aw1;
        aw0[0]=(__bf16)p0[0]; aw0[1]=(__bf16)p0[1]; aw0[2]=(__bf16)p0[2]; aw0[3]=(__bf16)p0[3];
        aw0[4]=(__bf16)p1[0]; aw0[5]=(__bf16)p1[1]; aw0[6]=(__bf16)p1[2]; aw0[7]=(__bf16)p1[3];
        aw1[0]=(__bf16)p2[0]; aw1[1]=(__bf16)p2[1]; aw1[2]=(__bf16)p2[2]; aw1[3]=(__bf16)p2[3];
        aw1[4]=(__bf16)p3[0]; aw1[5]=(__bf16)p3[1]; aw1[6]=(__bf16)p3[2]; aw1[7]=(__bf16)p3[3];
        f32x4 gacc = {0.f, 0.f, 0.f, 0.f};
        gacc = MFMA16(aw0, ae0, gacc);
        gacc = MFMA16(aw1, ae1, gacc);
        ghvp[t * 2 + 0] = pack2(gacc[0] * vacc[0], gacc[1] * vacc[1]);
        ghvp[t * 2 + 1] = pack2(gacc[2] * vacc[2], gacc[3] * vacc[3]);
    }

    // ---------------- W2^T fragments direct from global (A-op: [m=dout][k=j]) ----
    // w2f[c][i] = W2^T[dout = colb+l16][j = c*32+quad*8+i] = W2g[j*64 + dout]
    bf16x8 w2f[8];
#pragma unroll
    for (int c = 0; c < 8; ++c) {
        const float* src = W2g + (c * 32 + quad * 8) * 64 + colb + l16;
        bf16x8 f;
#pragma unroll
        for (int i = 0; i < 8; ++i) f[i] = (__bf16)src[i * 64];
        w2f[c] = f;
    }

    // ---------------- z state (lane layout: batch=l16, d=colb+quad*4+rg) ----
    f32x4 zv = *(const f32x4*)(Yg + row * 64 + colb + quad * 4);
    const float b1r  = b1g[tid];             // own j = tid
    const float w1tr = W1g[64 * 256 + tid];  // W1 time row

    const float dt = 0.125f;
    u32 kp[6][2];     // k_dz bf16x2: [stage][pair], d = colb + quad*4 + {0..3}
    float lp = 0.f;   // own-j partial of dlogp (batch = l16)

#define KV(s, g) frombits(((g) & 1) ? (kp[s][(g)>>1] >> 16) : (kp[s][(g)>>1] & 0xffffu))

#define S1A(g) (0.2f*KV(0,g))
#define S2A(g) (0.075f*KV(0,g) + 0.225f*KV(1,g))
#define S3A(g) ((44.f/45.f)*KV(0,g) + (-56.f/15.f)*KV(1,g) + (32.f/9.f)*KV(2,g))
#define S4A(g) ((19372.f/6561.f)*KV(0,g) + (-25360.f/2187.f)*KV(1,g) + \
                (64448.f/6561.f)*KV(2,g) + (-212.f/729.f)*KV(3,g))
#define S5A(g) ((9017.f/3168.f)*KV(0,g) + (-355.f/33.f)*KV(1,g) + \
                (46732.f/5247.f)*KV(2,g) + (49.f/176.f)*KV(3,g) + (-5103.f/18656.f)*KV(4,g))
#define CBA(g) ((35.f/384.f)*KV(0,g) + (500.f/1113.f)*KV(2,g) + (125.f/192.f)*KV(3,g) + \
                (-2187.f/6784.f)*KV(4,g) + (11.f/84.f)*KV(5,g))

    // matmul-1 tile: ua init = bw (bias in accumulator); h packed b64 to sH
#define MM1T(t) { \
    f32x4 ua = *(const f32x4*)(sBW + jb + (t)*16 + quad * 4); \
    ua = MFMA16(w1f[(t)*2 + 0], a10, ua); \
    ua = MFMA16(w1f[(t)*2 + 1], a11, ua); \
    float h0 = fast_tanh(ua[0]), h1 = fast_tanh(ua[1]); \
    float h2 = fast_tanh(ua[2]), h3 = fast_tanh(ua[3]); \
    u32 g0 = ghvp[(t)*2 + 0], g1 = ghvp[(t)*2 + 1]; \
    dv += frombits(g0 & 0xffffu) * (1.f - h0*h0); \
    dv += frombits(g0 >> 16)     * (1.f - h1*h1); \
    dv += frombits(g1 & 0xffffu) * (1.f - h2*h2); \
    dv += frombits(g1 >> 16)     * (1.f - h3*h3); \
    bf16x4 hv; hv[0]=(__bf16)h0; hv[1]=(__bf16)h1; hv[2]=(__bf16)h2; hv[3]=(__bf16)h3; \
    *(bf16x4*)(sH + l16 * 264 + jb + (t)*16 + quad * 4) = hv; }

#define MM2C(c) { \
    bf16x8 hf = *(const bf16x8*)(sH + l16 * 264 + (c)*32 + quad * 8); \
    fa = MFMA16(w2f[c], hf, fa); }

#define STAGE(st, CTI, DTB, A0, A1, A2, A3) { \
    const float ti = t0 + (CTI) * dt; \
    { \
        bf16x4 yv; \
        yv[0] = (__bf16)(zv[0] + dt * (A0)); \
        yv[1] = (__bf16)(zv[1] + dt * (A1)); \
        yv[2] = (__bf16)(zv[2] + dt * (A2)); \
        yv[3] = (__bf16)(zv[3] + dt * (A3)); \
        *(bf16x4*)(sY + l16 * 72 + colb + quad * 4) = yv; \
    } \
    sBW[tid] = b1r + ti * w1tr; \
    __syncthreads(); \
    bf16x8 a10 = *(const bf16x8*)(sY + l16 * 72 + quad * 8); \
    bf16x8 a11 = *(const bf16x8*)(sY + l16 * 72 + 32 + quad * 8); \
    float dv = 0.f; \
    MM1T(0) MM1T(1) MM1T(2) MM1T(3) \
    __syncthreads(); \
    f32x4 fa = *(const f32x4*)(sB2 + colb + quad * 4); \
    MM2C(0) MM2C(1) MM2C(2) MM2C(3) MM2C(4) MM2C(5) MM2C(6) MM2C(7) \
    kp[st][0] = pack2(fa[0], fa[1]); \
    kp[st][1] = pack2(fa[2], fa[3]); \
    dv += __shfl_xor(dv, 16); \
    dv += __shfl_xor(dv, 32); \
    lp -= (DTB) * dv; }

    for (int step = 0; step < 8; ++step) {
        const float t0 = dt * (float)step;
        STAGE(0, 0.f,     dt*(35.f/384.f),    0.f,    0.f,    0.f,    0.f)
        STAGE(1, 0.2f,    0.f,                S1A(0), S1A(1), S1A(2), S1A(3))
        STAGE(2, 0.3f,    dt*(500.f/1113.f),  S2A(0), S2A(1), S2A(2), S2A(3))
        STAGE(3, 0.8f,    dt*(125.f/192.f),   S3A(0), S3A(1), S3A(2), S3A(3))
        STAGE(4, 8.f/9.f, dt*(-2187.f/6784.f),S4A(0), S4A(1), S4A(2), S4A(3))
        STAGE(5, 1.f,     dt*(11.f/84.f),     S5A(0), S5A(1), S5A(2), S5A(3))
        zv[0] += dt * CBA(0);
        zv[1] += dt * CBA(1);
        zv[2] += dt * CBA(2);
        zv[3] += dt * CBA(3);
    }

    // ---------------- epilogue ----------------
    *(f32x4*)(Og + row * 64 + colb + quad * 4) = zv;
    float ss = zv[0]*zv[0] + zv[1]*zv[1] + zv[2]*zv[2] + zv[3]*zv[3];
    ss += __shfl_xor(ss, 16);
    ss += __shfl_xor(ss, 32);
    if (quad == 0) {
        sRedSS[wave * 16 + l16] = ss;
        sRedLP[wave * 16 + l16] = lp;
    }
    __syncthreads();
    if (tid < 16) {
        const float CLOG = -58.8120661f;  // -32*ln(2*pi)
        float sfull = sRedSS[tid] + sRedSS[16 + tid] + sRedSS[32 + tid] + sRedSS[48 + tid];
        float lfull = sRedLP[tid] + sRedLP[16 + tid] + sRedLP[32 + tid] + sRedLP[48 + tid];
        Og[32768 * 64 + blockIdx.x * 16 + tid] = CLOG - 0.5f * sfull - lfull;
    }
}

extern "C" void kernel_launch(void* const* d_in, const int* in_sizes, int n_in,
                              void* d_out, int out_size, void* d_ws, size_t ws_size,
                              hipStream_t stream) {
    const float* Yg  = (const float*)d_in[0];
    const float* Eg  = (const float*)d_in[1];
    const float* W1g = (const float*)d_in[2];  // [65][256]
    const float* b1g = (const float*)d_in[3];
    const float* W2g = (const float*)d_in[4];  // [256][64]
    const float* b2g = (const float*)d_in[5];
    float* Og = (float*)d_out;                 // z (32768*64) then log_px (32768)
    cnf_kernel<<<dim3(2048), dim3(256), 0, stream>>>(Yg, Eg, W1g, b1g, W2g, b2g, Og);
}

// Round 5
// 307.521 us; speedup vs baseline: 3.7356x; 1.1074x over previous
//
#include <hip/hip_runtime.h>

// CNF forward: 8 fixed dopri5 steps x 6 stages, rows independent.
// R10: R9 still spilled a few regs/stage (FETCH 142MB + WRITE 258MB scratch).
// VGPR_Count=84 = even arch/acc split of the 170 budget at (256,3); arch
// demand was ~55 + w2f 32 = 87 > 84 -> allocator kept w1f in acc but left
// w2f in arch, overflowing by a few regs. Structural fix instead of another
// placement fight: W2^T moves to a block-SHARED LDS buffer (sW2T, 33.8 KB,
// staged once, +1 ds_read_b128 per MM2 chunk; same stride/bank pattern as
// sH so conflicts unchanged). Arch demand ~55-65 <= 84 with slack -> zero
// spill by construction. LDS 46.8 KB -> 3 blocks/CU = 12 waves/CU.

typedef __bf16 bf16x8 __attribute__((ext_vector_type(8)));
typedef __bf16 bf16x4 __attribute__((ext_vector_type(4)));
typedef float  f32x4  __attribute__((ext_vector_type(4)));
typedef unsigned int u32;

#define MFMA16(a, b, c) __builtin_amdgcn_mfma_f32_16x16x32_bf16((a), (b), (c), 0, 0, 0)

__device__ __forceinline__ u32 bfbits(float x) {
    __bf16 b = (__bf16)x;                      // RNE fp32->bf16
    return (u32)__builtin_bit_cast(unsigned short, b);
}
__device__ __forceinline__ float frombits(u32 u16) {
    return __builtin_bit_cast(float, u16 << 16);
}
__device__ __forceinline__ u32 pack2(float lo, float hi) {
    return bfbits(lo) | (bfbits(hi) << 16);
}
__device__ __forceinline__ float fast_tanh(float x) {
    float e = __expf(2.0f * x);
    return 1.0f - 2.0f * __builtin_amdgcn_rcpf(e + 1.0f);
}

extern "C" __global__ void __launch_bounds__(256, 3)
cnf_kernel(const float* __restrict__ Yg, const float* __restrict__ Eg,
           const float* __restrict__ W1g, const float* __restrict__ b1g,
           const float* __restrict__ W2g, const float* __restrict__ b2g,
           float* __restrict__ Og)
{
    // ---- LDS (~46.8 KB; 3 blocks/CU) ----
    __shared__ __align__(16) __bf16 sW2T[64 * 264]; // W2^T [dout][j], shared by all waves
    __shared__ __align__(16) __bf16 sY[16 * 72];    // y buf [batch][d]
    __shared__ __align__(16) __bf16 sH[16 * 264];   // h buf [batch][j]
    __shared__ float sBW[256];                      // per-stage b1 + t*W1_t
    __shared__ __align__(16) float sB2[64];         // b2 (keeps bb2 out of arch regs)
    __shared__ float sRedSS[64], sRedLP[64];

    const int tid  = threadIdx.x;
    const int wave = tid >> 6;        // 0..3: wave's slot within the group
    const int lane = tid & 63;
    const int quad = lane >> 4;
    const int l16  = lane & 15;
    const int colb = wave * 16;       // own output-col tile base
    const int jb   = wave * 64;       // own hidden-j base (4 tiles of 16)
    const int row  = blockIdx.x * 16 + l16;   // this lane's batch row

    if (tid < 64) sB2[tid] = b2g[tid];

    // ---------------- stage W2^T into shared LDS: sW2T[d*264 + j] = W2[j][d] ----
    for (int idx = tid; idx < 256 * 64; idx += 256) {
        int j = idx >> 6, d = idx & 63;
        sW2T[d * 264 + j] = (__bf16)W2g[idx];
    }

    // ---------------- e fragments direct from global ----------------
    // ae: lane (l16=batch, quad) holds e[row][d = quad*8 + i] (+32 for ae1)
    bf16x8 ae0, ae1;
    {
        f32x4 ea = *(const f32x4*)(Eg + row * 64 + quad * 8);
        f32x4 eb = *(const f32x4*)(Eg + row * 64 + quad * 8 + 4);
        f32x4 ec = *(const f32x4*)(Eg + row * 64 + 32 + quad * 8);
        f32x4 ed = *(const f32x4*)(Eg + row * 64 + 32 + quad * 8 + 4);
        ae0[0]=(__bf16)ea[0]; ae0[1]=(__bf16)ea[1]; ae0[2]=(__bf16)ea[2]; ae0[3]=(__bf16)ea[3];
        ae0[4]=(__bf16)eb[0]; ae0[5]=(__bf16)eb[1]; ae0[6]=(__bf16)eb[2]; ae0[7]=(__bf16)eb[3];
        ae1[0]=(__bf16)ec[0]; ae1[1]=(__bf16)ec[1]; ae1[2]=(__bf16)ec[2]; ae1[3]=(__bf16)ec[3];
        ae1[4]=(__bf16)ed[0]; ae1[5]=(__bf16)ed[1]; ae1[6]=(__bf16)ed[2]; ae1[7]=(__bf16)ed[3];
    }

    // ---------------- W1 fragments direct from global (A-op: [m=j][k=d]) ----
    // w1f[t*2+h][i] = W1^T[j = jb+t*16+l16][d = h*32+quad*8+i] = W1g[d*256 + j]
    bf16x8 w1f[8];
#pragma unroll
    for (int t = 0; t < 4; ++t) {
#pragma unroll
        for (int h = 0; h < 2; ++h) {
            const float* src = W1g + (h * 32 + quad * 8) * 256 + jb + t * 16 + l16;
            bf16x8 f;
#pragma unroll
            for (int i = 0; i < 8; ++i) f[i] = (__bf16)src[i * 256];
            w1f[t * 2 + h] = f;
        }
    }

    // ---------------- ghv[j][batch] = gh0 .* v, layout j=quad*4+rg, batch=l16 ----
    // v^T = (e@W1a)^T via operand swap: A=W1a^T[m=j][k=d], B=e^T[k=d][n=b]
    //   -> C[j=quad*4+rg][b=l16]  (no transpose scratch needed)
    // gh0^T = W2@e^T: A=W2[m=j][k=d] (contiguous rows of W2g), B=e^T
    u32 ghvp[8];   // [tile*2 + pair], bf16x2 packed
#pragma unroll
    for (int t = 0; t < 4; ++t) {
        f32x4 vacc = {0.f, 0.f, 0.f, 0.f};
        vacc = MFMA16(w1f[t * 2 + 0], ae0, vacc);
        vacc = MFMA16(w1f[t * 2 + 1], ae1, vacc);
        const float* wr = W2g + (jb + t * 16 + l16) * 64;
        f32x4 p0 = *(const f32x4*)(wr + quad * 8);
        f32x4 p1 = *(const f32x4*)(wr + quad * 8 + 4);
        f32x4 p2 = *(const f32x4*)(wr + 32 + quad * 8);
        f32x4 p3 = *(const f32x4*)(wr + 32 + quad * 8 + 4);
        bf16x8 aw0, aw1;
        aw0[0]=(__bf16)p0[0]; aw0[1]=(__bf16)p0[1]; aw0[2]=(__bf16)p0[2]; aw0[3]=(__bf16)p0[3];
        aw0[4]=(__bf16)p1[0]; aw0[5]=(__bf16)p1[1]; aw0[6]=(__bf16)p1[2]; aw0[7]=(__bf16)p1[3];
        aw1[0]=(__bf16)p2[0]; aw1[1]=(__bf16)p2[1]; aw1[2]=(__bf16)p2[2]; aw1[3]=(__bf16)p2[3];
        aw1[4]=(__bf16)p3[0]; aw1[5]=(__bf16)p3[1]; aw1[6]=(__bf16)p3[2]; aw1[7]=(__bf16)p3[3];
        f32x4 gacc = {0.f, 0.f, 0.f, 0.f};
        gacc = MFMA16(aw0, ae0, gacc);
        gacc = MFMA16(aw1, ae1, gacc);
        ghvp[t * 2 + 0] = pack2(gacc[0] * vacc[0], gacc[1] * vacc[1]);
        ghvp[t * 2 + 1] = pack2(gacc[2] * vacc[2], gacc[3] * vacc[3]);
    }

    // ---------------- z state (lane layout: batch=l16, d=colb+quad*4+rg) ----
    f32x4 zv = *(const f32x4*)(Yg + row * 64 + colb + quad * 4);
    const float b1r  = b1g[tid];             // own j = tid
    const float w1tr = W1g[64 * 256 + tid];  // W1 time row

    const float dt = 0.125f;
    u32 kp[6][2];     // k_dz bf16x2: [stage][pair], d = colb + quad*4 + {0..3}
    float lp = 0.f;   // own-j partial of dlogp (batch = l16)

#define KV(s, g) frombits(((g) & 1) ? (kp[s][(g)>>1] >> 16) : (kp[s][(g)>>1] & 0xffffu))

#define S1A(g) (0.2f*KV(0,g))
#define S2A(g) (0.075f*KV(0,g) + 0.225f*KV(1,g))
#define S3A(g) ((44.f/45.f)*KV(0,g) + (-56.f/15.f)*KV(1,g) + (32.f/9.f)*KV(2,g))
#define S4A(g) ((19372.f/6561.f)*KV(0,g) + (-25360.f/2187.f)*KV(1,g) + \
                (64448.f/6561.f)*KV(2,g) + (-212.f/729.f)*KV(3,g))
#define S5A(g) ((9017.f/3168.f)*KV(0,g) + (-355.f/33.f)*KV(1,g) + \
                (46732.f/5247.f)*KV(2,g) + (49.f/176.f)*KV(3,g) + (-5103.f/18656.f)*KV(4,g))
#define CBA(g) ((35.f/384.f)*KV(0,g) + (500.f/1113.f)*KV(2,g) + (125.f/192.f)*KV(3,g) + \
                (-2187.f/6784.f)*KV(4,g) + (11.f/84.f)*KV(5,g))

    // matmul-1 tile: ua init = bw (bias in accumulator); h packed b64 to sH
#define MM1T(t) { \
    f32x4 ua = *(const f32x4*)(sBW + jb + (t)*16 + quad * 4); \
    ua = MFMA16(w1f[(t)*2 + 0], a10, ua); \
    ua = MFMA16(w1f[(t)*2 + 1], a11, ua); \
    float h0 = fast_tanh(ua[0]), h1 = fast_tanh(ua[1]); \
    float h2 = fast_tanh(ua[2]), h3 = fast_tanh(ua[3]); \
    u32 g0 = ghvp[(t)*2 + 0], g1 = ghvp[(t)*2 + 1]; \
    dv += frombits(g0 & 0xffffu) * (1.f - h0*h0); \
    dv += frombits(g0 >> 16)     * (1.f - h1*h1); \
    dv += frombits(g1 & 0xffffu) * (1.f - h2*h2); \
    dv += frombits(g1 >> 16)     * (1.f - h3*h3); \
    bf16x4 hv; hv[0]=(__bf16)h0; hv[1]=(__bf16)h1; hv[2]=(__bf16)h2; hv[3]=(__bf16)h3; \
    *(bf16x4*)(sH + l16 * 264 + jb + (t)*16 + quad * 4) = hv; }

#define MM2C(c) { \
    bf16x8 hf = *(const bf16x8*)(sH + l16 * 264 + (c)*32 + quad * 8); \
    bf16x8 wf = *(const bf16x8*)(sW2T + (colb + l16) * 264 + (c)*32 + quad * 8); \
    fa = MFMA16(wf, hf, fa); }

#define STAGE(st, CTI, DTB, A0, A1, A2, A3) { \
    const float ti = t0 + (CTI) * dt; \
    { \
        bf16x4 yv; \
        yv[0] = (__bf16)(zv[0] + dt * (A0)); \
        yv[1] = (__bf16)(zv[1] + dt * (A1)); \
        yv[2] = (__bf16)(zv[2] + dt * (A2)); \
        yv[3] = (__bf16)(zv[3] + dt * (A3)); \
        *(bf16x4*)(sY + l16 * 72 + colb + quad * 4) = yv; \
    } \
    sBW[tid] = b1r + ti * w1tr; \
    __syncthreads(); \
    bf16x8 a10 = *(const bf16x8*)(sY + l16 * 72 + quad * 8); \
    bf16x8 a11 = *(const bf16x8*)(sY + l16 * 72 + 32 + quad * 8); \
    float dv = 0.f; \
    MM1T(0) MM1T(1) MM1T(2) MM1T(3) \
    __syncthreads(); \
    f32x4 fa = *(const f32x4*)(sB2 + colb + quad * 4); \
    MM2C(0) MM2C(1) MM2C(2) MM2C(3) MM2C(4) MM2C(5) MM2C(6) MM2C(7) \
    kp[st][0] = pack2(fa[0], fa[1]); \
    kp[st][1] = pack2(fa[2], fa[3]); \
    dv += __shfl_xor(dv, 16); \
    dv += __shfl_xor(dv, 32); \
    lp -= (DTB) * dv; }

    for (int step = 0; step < 8; ++step) {
        const float t0 = dt * (float)step;
        STAGE(0, 0.f,     dt*(35.f/384.f),    0.f,    0.f,    0.f,    0.f)
        STAGE(1, 0.2f,    0.f,                S1A(0), S1A(1), S1A(2), S1A(3))
        STAGE(2, 0.3f,    dt*(500.f/1113.f),  S2A(0), S2A(1), S2A(2), S2A(3))
        STAGE(3, 0.8f,    dt*(125.f/192.f),   S3A(0), S3A(1), S3A(2), S3A(3))
        STAGE(4, 8.f/9.f, dt*(-2187.f/6784.f),S4A(0), S4A(1), S4A(2), S4A(3))
        STAGE(5, 1.f,     dt*(11.f/84.f),     S5A(0), S5A(1), S5A(2), S5A(3))
        zv[0] += dt * CBA(0);
        zv[1] += dt * CBA(1);
        zv[2] += dt * CBA(2);
        zv[3] += dt * CBA(3);
    }

    // ---------------- epilogue ----------------
    *(f32x4*)(Og + row * 64 + colb + quad * 4) = zv;
    float ss = zv[0]*zv[0] + zv[1]*zv[1] + zv[2]*zv[2] + zv[3]*zv[3];
    ss += __shfl_xor(ss, 16);
    ss += __shfl_xor(ss, 32);
    if (quad == 0) {
        sRedSS[wave * 16 + l16] = ss;
        sRedLP[wave * 16 + l16] = lp;
    }
    __syncthreads();
    if (tid < 16) {
        const float CLOG = -58.8120661f;  // -32*ln(2*pi)
        float sfull = sRedSS[tid] + sRedSS[16 + tid] + sRedSS[32 + tid] + sRedSS[48 + tid];
        float lfull = sRedLP[tid] + sRedLP[16 + tid] + sRedLP[32 + tid] + sRedLP[48 + tid];
        Og[32768 * 64 + blockIdx.x * 16 + tid] = CLOG - 0.5f * sfull - lfull;
    }
}

extern "C" void kernel_launch(void* const* d_in, const int* in_sizes, int n_in,
                              void* d_out, int out_size, void* d_ws, size_t ws_size,
                              hipStream_t stream) {
    const float* Yg  = (const float*)d_in[0];
    const float* Eg  = (const float*)d_in[1];
    const float* W1g = (const float*)d_in[2];  // [65][256]
    const float* b1g = (const float*)d_in[3];
    const float* W2g = (const float*)d_in[4];  // [256][64]
    const float* b2g = (const float*)d_in[5];
    float* Og = (float*)d_out;                 // z (32768*64) then log_px (32768)
    cnf_kernel<<<dim3(2048), dim3(256), 0, stream>>>(Yg, Eg, W1g, b1g, W2g, b2g, Og);
}

// Round 6
// 304.326 us; speedup vs baseline: 3.7749x; 1.0105x over previous
//
#include <hip/hip_runtime.h>

// CNF forward: 8 fixed dopri5 steps x 6 stages, rows independent.
// R11: R10 fixed the spill (FETCH 8.8MB) and sits at 278us, VALUBusy 57%,
// MfmaUtil 17%, 12 waves/CU (reg-capped: ~152-reg working set, arch 80 +
// acc 64; >12 waves re-enters the R6-R8 spill cliff). Remaining wall is
// ~40% dependency stall. This round cuts chain lengths + instr count:
//  * MM2 accumulator split into 2 interleaved chains (fa0/fa1) -- halves
//    the 8-deep dependent-MFMA serial chain per stage.
//  * ghv kept UNPACKED as 16 floats (+8 arch regs, 152 total <= 170):
//    removes 16 lshl/stage from the dv dependency path.
//  * dv/lp skipped in the B_TAB==0 stage (dv was multiplied by 0).

typedef __bf16 bf16x8 __attribute__((ext_vector_type(8)));
typedef __bf16 bf16x4 __attribute__((ext_vector_type(4)));
typedef float  f32x4  __attribute__((ext_vector_type(4)));
typedef unsigned int u32;

#define MFMA16(a, b, c) __builtin_amdgcn_mfma_f32_16x16x32_bf16((a), (b), (c), 0, 0, 0)

__device__ __forceinline__ u32 bfbits(float x) {
    __bf16 b = (__bf16)x;                      // RNE fp32->bf16
    return (u32)__builtin_bit_cast(unsigned short, b);
}
__device__ __forceinline__ float frombits(u32 u16) {
    return __builtin_bit_cast(float, u16 << 16);
}
__device__ __forceinline__ u32 pack2(float lo, float hi) {
    return bfbits(lo) | (bfbits(hi) << 16);
}
__device__ __forceinline__ float fast_tanh(float x) {
    float e = __expf(2.0f * x);
    return 1.0f - 2.0f * __builtin_amdgcn_rcpf(e + 1.0f);
}

extern "C" __global__ void __launch_bounds__(256, 3)
cnf_kernel(const float* __restrict__ Yg, const float* __restrict__ Eg,
           const float* __restrict__ W1g, const float* __restrict__ b1g,
           const float* __restrict__ W2g, const float* __restrict__ b2g,
           float* __restrict__ Og)
{
    // ---- LDS (~46.8 KB; 3 blocks/CU, matching the 12-wave reg cap) ----
    __shared__ __align__(16) __bf16 sW2T[64 * 264]; // W2^T [dout][j], shared by all waves
    __shared__ __align__(16) __bf16 sY[16 * 72];    // y buf [batch][d]
    __shared__ __align__(16) __bf16 sH[16 * 264];   // h buf [batch][j]
    __shared__ float sBW[256];                      // per-stage b1 + t*W1_t
    __shared__ __align__(16) float sB2[64];         // b2 (keeps bb2 out of arch regs)
    __shared__ float sRedSS[64], sRedLP[64];

    const int tid  = threadIdx.x;
    const int wave = tid >> 6;        // 0..3: wave's slot within the group
    const int lane = tid & 63;
    const int quad = lane >> 4;
    const int l16  = lane & 15;
    const int colb = wave * 16;       // own output-col tile base
    const int jb   = wave * 64;       // own hidden-j base (4 tiles of 16)
    const int row  = blockIdx.x * 16 + l16;   // this lane's batch row

    if (tid < 64) sB2[tid] = b2g[tid];

    // ---------------- stage W2^T into shared LDS: sW2T[d*264 + j] = W2[j][d] ----
    for (int idx = tid; idx < 256 * 64; idx += 256) {
        int j = idx >> 6, d = idx & 63;
        sW2T[d * 264 + j] = (__bf16)W2g[idx];
    }

    // ---------------- e fragments direct from global ----------------
    // ae: lane (l16=batch, quad) holds e[row][d = quad*8 + i] (+32 for ae1)
    bf16x8 ae0, ae1;
    {
        f32x4 ea = *(const f32x4*)(Eg + row * 64 + quad * 8);
        f32x4 eb = *(const f32x4*)(Eg + row * 64 + quad * 8 + 4);
        f32x4 ec = *(const f32x4*)(Eg + row * 64 + 32 + quad * 8);
        f32x4 ed = *(const f32x4*)(Eg + row * 64 + 32 + quad * 8 + 4);
        ae0[0]=(__bf16)ea[0]; ae0[1]=(__bf16)ea[1]; ae0[2]=(__bf16)ea[2]; ae0[3]=(__bf16)ea[3];
        ae0[4]=(__bf16)eb[0]; ae0[5]=(__bf16)eb[1]; ae0[6]=(__bf16)eb[2]; ae0[7]=(__bf16)eb[3];
        ae1[0]=(__bf16)ec[0]; ae1[1]=(__bf16)ec[1]; ae1[2]=(__bf16)ec[2]; ae1[3]=(__bf16)ec[3];
        ae1[4]=(__bf16)ed[0]; ae1[5]=(__bf16)ed[1]; ae1[6]=(__bf16)ed[2]; ae1[7]=(__bf16)ed[3];
    }

    // ---------------- W1 fragments direct from global (A-op: [m=j][k=d]) ----
    // w1f[t*2+h][i] = W1^T[j = jb+t*16+l16][d = h*32+quad*8+i] = W1g[d*256 + j]
    bf16x8 w1f[8];
#pragma unroll
    for (int t = 0; t < 4; ++t) {
#pragma unroll
        for (int h = 0; h < 2; ++h) {
            const float* src = W1g + (h * 32 + quad * 8) * 256 + jb + t * 16 + l16;
            bf16x8 f;
#pragma unroll
            for (int i = 0; i < 8; ++i) f[i] = (__bf16)src[i * 256];
            w1f[t * 2 + h] = f;
        }
    }

    // ---------------- ghf[j][batch] = gh0 .* v, layout j=quad*4+rg, batch=l16 ----
    // v^T = (e@W1a)^T via operand swap: A=W1a^T[m=j][k=d], B=e^T[k=d][n=b]
    //   -> C[j=quad*4+rg][b=l16]  (no transpose scratch needed)
    // gh0^T = W2@e^T: A=W2[m=j][k=d] (contiguous rows of W2g), B=e^T
    float ghf[16];   // [tile*4 + rg], unpacked f32 (keeps dv chain shift-free)
#pragma unroll
    for (int t = 0; t < 4; ++t) {
        f32x4 vacc = {0.f, 0.f, 0.f, 0.f};
        vacc = MFMA16(w1f[t * 2 + 0], ae0, vacc);
        vacc = MFMA16(w1f[t * 2 + 1], ae1, vacc);
        const float* wr = W2g + (jb + t * 16 + l16) * 64;
        f32x4 p0 = *(const f32x4*)(wr + quad * 8);
        f32x4 p1 = *(const f32x4*)(wr + quad * 8 + 4);
        f32x4 p2 = *(const f32x4*)(wr + 32 + quad * 8);
        f32x4 p3 = *(const f32x4*)(wr + 32 + quad * 8 + 4);
        bf16x8 aw0, aw1;
        aw0[0]=(__bf16)p0[0]; aw0[1]=(__bf16)p0[1]; aw0[2]=(__bf16)p0[2]; aw0[3]=(__bf16)p0[3];
        aw0[4]=(__bf16)p1[0]; aw0[5]=(__bf16)p1[1]; aw0[6]=(__bf16)p1[2]; aw0[7]=(__bf16)p1[3];
        aw1[0]=(__bf16)p2[0]; aw1[1]=(__bf16)p2[1]; aw1[2]=(__bf16)p2[2]; aw1[3]=(__bf16)p2[3];
        aw1[4]=(__bf16)p3[0]; aw1[5]=(__bf16)p3[1]; aw1[6]=(__bf16)p3[2]; aw1[7]=(__bf16)p3[3];
        f32x4 gacc = {0.f, 0.f, 0.f, 0.f};
        gacc = MFMA16(aw0, ae0, gacc);
        gacc = MFMA16(aw1, ae1, gacc);
        ghf[t * 4 + 0] = gacc[0] * vacc[0];
        ghf[t * 4 + 1] = gacc[1] * vacc[1];
        ghf[t * 4 + 2] = gacc[2] * vacc[2];
        ghf[t * 4 + 3] = gacc[3] * vacc[3];
    }

    // ---------------- z state (lane layout: batch=l16, d=colb+quad*4+rg) ----
    f32x4 zv = *(const f32x4*)(Yg + row * 64 + colb + quad * 4);
    const float b1r  = b1g[tid];             // own j = tid
    const float w1tr = W1g[64 * 256 + tid];  // W1 time row

    const float dt = 0.125f;
    u32 kp[6][2];     // k_dz bf16x2: [stage][pair], d = colb + quad*4 + {0..3}
    float lp = 0.f;   // own-j partial of dlogp (batch = l16)

#define KV(s, g) frombits(((g) & 1) ? (kp[s][(g)>>1] >> 16) : (kp[s][(g)>>1] & 0xffffu))

#define S1A(g) (0.2f*KV(0,g))
#define S2A(g) (0.075f*KV(0,g) + 0.225f*KV(1,g))
#define S3A(g) ((44.f/45.f)*KV(0,g) + (-56.f/15.f)*KV(1,g) + (32.f/9.f)*KV(2,g))
#define S4A(g) ((19372.f/6561.f)*KV(0,g) + (-25360.f/2187.f)*KV(1,g) + \
                (64448.f/6561.f)*KV(2,g) + (-212.f/729.f)*KV(3,g))
#define S5A(g) ((9017.f/3168.f)*KV(0,g) + (-355.f/33.f)*KV(1,g) + \
                (46732.f/5247.f)*KV(2,g) + (49.f/176.f)*KV(3,g) + (-5103.f/18656.f)*KV(4,g))
#define CBA(g) ((35.f/384.f)*KV(0,g) + (500.f/1113.f)*KV(2,g) + (125.f/192.f)*KV(3,g) + \
                (-2187.f/6784.f)*KV(4,g) + (11.f/84.f)*KV(5,g))

    // matmul-1 tile: ua init = bw (bias in accumulator); h packed b64 to sH.
    // DODV is a literal 0/1: dv math folded away when the stage's B_TAB weight
    // is 0 (h stays live via the sH store -- no DCE hazard).
#define MM1T(t, DODV) { \
    f32x4 ua = *(const f32x4*)(sBW + jb + (t)*16 + quad * 4); \
    ua = MFMA16(w1f[(t)*2 + 0], a10, ua); \
    ua = MFMA16(w1f[(t)*2 + 1], a11, ua); \
    float h0 = fast_tanh(ua[0]), h1 = fast_tanh(ua[1]); \
    float h2 = fast_tanh(ua[2]), h3 = fast_tanh(ua[3]); \
    if (DODV) { \
        dv += ghf[(t)*4 + 0] * (1.f - h0*h0); \
        dv += ghf[(t)*4 + 1] * (1.f - h1*h1); \
        dv += ghf[(t)*4 + 2] * (1.f - h2*h2); \
        dv += ghf[(t)*4 + 3] * (1.f - h3*h3); \
    } \
    bf16x4 hv; hv[0]=(__bf16)h0; hv[1]=(__bf16)h1; hv[2]=(__bf16)h2; hv[3]=(__bf16)h3; \
    *(bf16x4*)(sH + l16 * 264 + jb + (t)*16 + quad * 4) = hv; }

#define MM2C(c, acc) { \
    bf16x8 hf = *(const bf16x8*)(sH + l16 * 264 + (c)*32 + quad * 8); \
    bf16x8 wf = *(const bf16x8*)(sW2T + (colb + l16) * 264 + (c)*32 + quad * 8); \
    acc = MFMA16(wf, hf, acc); }

#define STAGE(st, CTI, DTB, DODV, A0, A1, A2, A3) { \
    const float ti = t0 + (CTI) * dt; \
    { \
        bf16x4 yv; \
        yv[0] = (__bf16)(zv[0] + dt * (A0)); \
        yv[1] = (__bf16)(zv[1] + dt * (A1)); \
        yv[2] = (__bf16)(zv[2] + dt * (A2)); \
        yv[3] = (__bf16)(zv[3] + dt * (A3)); \
        *(bf16x4*)(sY + l16 * 72 + colb + quad * 4) = yv; \
    } \
    sBW[tid] = b1r + ti * w1tr; \
    __syncthreads(); \
    bf16x8 a10 = *(const bf16x8*)(sY + l16 * 72 + quad * 8); \
    bf16x8 a11 = *(const bf16x8*)(sY + l16 * 72 + 32 + quad * 8); \
    float dv = 0.f; \
    MM1T(0, DODV) MM1T(1, DODV) MM1T(2, DODV) MM1T(3, DODV) \
    __syncthreads(); \
    f32x4 fa0 = *(const f32x4*)(sB2 + colb + quad * 4); \
    f32x4 fa1 = {0.f, 0.f, 0.f, 0.f}; \
    MM2C(0, fa0) MM2C(1, fa1) MM2C(2, fa0) MM2C(3, fa1) \
    MM2C(4, fa0) MM2C(5, fa1) MM2C(6, fa0) MM2C(7, fa1) \
    f32x4 fa = fa0 + fa1; \
    kp[st][0] = pack2(fa[0], fa[1]); \
    kp[st][1] = pack2(fa[2], fa[3]); \
    if (DODV) { \
        dv += __shfl_xor(dv, 16); \
        dv += __shfl_xor(dv, 32); \
        lp -= (DTB) * dv; \
    } }

    for (int step = 0; step < 8; ++step) {
        const float t0 = dt * (float)step;
        STAGE(0, 0.f,     dt*(35.f/384.f),    1, 0.f,    0.f,    0.f,    0.f)
        STAGE(1, 0.2f,    0.f,                0, S1A(0), S1A(1), S1A(2), S1A(3))
        STAGE(2, 0.3f,    dt*(500.f/1113.f),  1, S2A(0), S2A(1), S2A(2), S2A(3))
        STAGE(3, 0.8f,    dt*(125.f/192.f),   1, S3A(0), S3A(1), S3A(2), S3A(3))
        STAGE(4, 8.f/9.f, dt*(-2187.f/6784.f),1, S4A(0), S4A(1), S4A(2), S4A(3))
        STAGE(5, 1.f,     dt*(11.f/84.f),     1, S5A(0), S5A(1), S5A(2), S5A(3))
        zv[0] += dt * CBA(0);
        zv[1] += dt * CBA(1);
        zv[2] += dt * CBA(2);
        zv[3] += dt * CBA(3);
    }

    // ---------------- epilogue ----------------
    *(f32x4*)(Og + row * 64 + colb + quad * 4) = zv;
    float ss = zv[0]*zv[0] + zv[1]*zv[1] + zv[2]*zv[2] + zv[3]*zv[3];
    ss += __shfl_xor(ss, 16);
    ss += __shfl_xor(ss, 32);
    if (quad == 0) {
        sRedSS[wave * 16 + l16] = ss;
        sRedLP[wave * 16 + l16] = lp;
    }
    __syncthreads();
    if (tid < 16) {
        const float CLOG = -58.8120661f;  // -32*ln(2*pi)
        float sfull = sRedSS[tid] + sRedSS[16 + tid] + sRedSS[32 + tid] + sRedSS[48 + tid];
        float lfull = sRedLP[tid] + sRedLP[16 + tid] + sRedLP[32 + tid] + sRedLP[48 + tid];
        Og[32768 * 64 + blockIdx.x * 16 + tid] = CLOG - 0.5f * sfull - lfull;
    }
}

extern "C" void kernel_launch(void* const* d_in, const int* in_sizes, int n_in,
                              void* d_out, int out_size, void* d_ws, size_t ws_size,
                              hipStream_t stream) {
    const float* Yg  = (const float*)d_in[0];
    const float* Eg  = (const float*)d_in[1];
    const float* W1g = (const float*)d_in[2];  // [65][256]
    const float* b1g = (const float*)d_in[3];
    const float* W2g = (const float*)d_in[4];  // [256][64]
    const float* b2g = (const float*)d_in[5];
    float* Og = (float*)d_out;                 // z (32768*64) then log_px (32768)
    cnf_kernel<<<dim3(2048), dim3(256), 0, stream>>>(Yg, Eg, W1g, b1g, W2g, b2g, Og);
}